// Round 1
// baseline (647.496 us; speedup 1.0000x reference)
//
#include <hip/hip_runtime.h>

// ---------------------------------------------------------------------------
// Fused attention: Q/K/V = x@W^T + b ; RoPE(Q,K) ; softmax(QK^T/sqrt(D)) @ V
// B=32 S=1024 D=768.  All GEMMs via fp16 MFMA (16x16x32), fp32 accumulate.
// m97-style gemm_bt: 128x128 tile, BK=32, 4 waves, global_load_lds width=16.
// ---------------------------------------------------------------------------

typedef __attribute__((ext_vector_type(8))) _Float16 f16x8;
typedef __attribute__((ext_vector_type(4))) float    f32x4;

__device__ __forceinline__ unsigned short f2h(float f) {
    _Float16 h = (_Float16)f;
    return __builtin_bit_cast(unsigned short, h);
}

__device__ __forceinline__ void async_ld16(const void* g, void* l) {
    __builtin_amdgcn_global_load_lds(
        (const __attribute__((address_space(1))) void*)g,
        (__attribute__((address_space(3))) void*)l, 16, 0, 0);
}

// MODE 0: projection + bias[col] + RoPE + scale, fp16 out, row stride 768 (Q,K)
// MODE 1: projection + bias[row], out transposed to [b][d][s] fp16 (V^T)
// MODE 2: scores: fp32 out [q][k], batched
// MODE 3: PV: fp32 out [q][d] -> d_out, batched
template<int MODE>
__global__ __launch_bounds__(256)
void gemm_bt(const unsigned short* __restrict__ A,
             const unsigned short* __restrict__ B,
             void* __restrict__ Cv,
             const float* __restrict__ bias,
             int K, int lda, int ldb,
             long long sAz, long long sBz, long long sCz,
             float scale)
{
    __shared__ __align__(16) unsigned short sA[128 * 32];
    __shared__ __align__(16) unsigned short sB[128 * 32];

    const int tid  = threadIdx.x;
    const int lane = tid & 63;
    const int wave = tid >> 6;
    const int wrow = (wave >> 1) * 64;   // 2x2 wave grid, 64x64 per wave
    const int wcol = (wave & 1) * 64;
    const int quad = lane >> 4;
    const int l15  = lane & 15;

    const int m0 = blockIdx.y * 128;
    const int n0 = blockIdx.x * 128;
    const int z  = blockIdx.z;

    const unsigned short* Ab = A + (size_t)z * sAz;
    const unsigned short* Bb = B + (size_t)z * sBz;

    const int srow0 = tid >> 2;        // staging row within 64-row half
    const int sk    = (tid & 3) * 8;   // staging k-offset (8 halves = 16B)

    f32x4 acc[4][4] = {};

    for (int kt = 0; kt < K; kt += 32) {
        __syncthreads();  // previous tile's ds_reads done before overwrite
        // A tile 128x32 -> LDS row-major [row][k] (8KB), 2 chunks/thread
        async_ld16(Ab + (size_t)(m0 +      srow0) * lda + kt + sk, &sA[tid * 8]);
        async_ld16(Ab + (size_t)(m0 + 64 + srow0) * lda + kt + sk, &sA[2048 + tid * 8]);
        async_ld16(Bb + (size_t)(n0 +      srow0) * ldb + kt + sk, &sB[tid * 8]);
        async_ld16(Bb + (size_t)(n0 + 64 + srow0) * ldb + kt + sk, &sB[2048 + tid * 8]);
        __syncthreads();  // compiler drains vmcnt before barrier

        f16x8 af[4], bfr[4];
        #pragma unroll
        for (int mi = 0; mi < 4; ++mi)
            af[mi] = *(const f16x8*)&sA[(wrow + mi * 16 + l15) * 32 + quad * 8];
        #pragma unroll
        for (int ni = 0; ni < 4; ++ni)
            bfr[ni] = *(const f16x8*)&sB[(wcol + ni * 16 + l15) * 32 + quad * 8];

        #pragma unroll
        for (int mi = 0; mi < 4; ++mi)
            #pragma unroll
            for (int ni = 0; ni < 4; ++ni)
                acc[mi][ni] = __builtin_amdgcn_mfma_f32_16x16x32_f16(
                    af[mi], bfr[ni], acc[mi][ni], 0, 0, 0);
    }

    // Epilogue. C/D layout: col = lane&15, row = quad*4 + reg  [m89-verified]
    #pragma unroll
    for (int mi = 0; mi < 4; ++mi) {
        #pragma unroll
        for (int ni = 0; ni < 4; ++ni) {
            #pragma unroll
            for (int reg = 0; reg < 4; ++reg) {
                const int grow = m0 + wrow + mi * 16 + quad * 4 + reg;
                const int gcol = n0 + wcol + ni * 16 + l15;
                float v = acc[mi][ni][reg];
                if constexpr (MODE == 0) {
                    v += bias[gcol];
                    // RoPE partner (adjacent column) lives in lane^1
                    const float other = __shfl_xor(v, 1);
                    const int   s     = grow & 1023;
                    // inv_freq[i] = 2^(-i * 2*log2(10000)/768)
                    const float invf  = exp2f((float)(gcol >> 1) * -0.03460341765507773f);
                    const float ang   = (float)s * invf;
                    float sn, cs;
                    __sincosf(ang, &sn, &cs);
                    const float r = (gcol & 1) ? (other * sn + v * cs)   // x1*sin + x2*cos
                                               : (v * cs - other * sn);  // x1*cos - x2*sin
                    ((unsigned short*)Cv)[(size_t)grow * 768 + gcol] = f2h(r * scale);
                } else if constexpr (MODE == 1) {
                    v += bias[grow];  // bias indexed by output feature = row (d)
                    const int b = gcol >> 10, s = gcol & 1023;
                    ((unsigned short*)Cv)[(size_t)b * (768 * 1024)
                                          + (size_t)grow * 1024 + s] = f2h(v);
                } else if constexpr (MODE == 2) {
                    (((float*)Cv) + (size_t)z * sCz)[(size_t)grow * 1024 + gcol] = v;
                } else {
                    (((float*)Cv) + (size_t)z * sCz)[(size_t)grow * 768 + gcol] = v;
                }
            }
        }
    }
}

__global__ __launch_bounds__(256)
void softmax_rows(const float* __restrict__ S, unsigned short* __restrict__ P)
{
    const int row = blockIdx.x;           // 32*1024 rows
    const int tid = threadIdx.x;
    const float4 v = ((const float4*)(S + (size_t)row * 1024))[tid];

    float m = fmaxf(fmaxf(v.x, v.y), fmaxf(v.z, v.w));
    #pragma unroll
    for (int o = 1; o < 64; o <<= 1) m = fmaxf(m, __shfl_xor(m, o));
    __shared__ float redm[4];
    __shared__ float reds[4];
    const int wave = tid >> 6, lane = tid & 63;
    if (lane == 0) redm[wave] = m;
    __syncthreads();
    m = fmaxf(fmaxf(redm[0], redm[1]), fmaxf(redm[2], redm[3]));

    const float e0 = __expf(v.x - m), e1 = __expf(v.y - m);
    const float e2 = __expf(v.z - m), e3 = __expf(v.w - m);
    float sum = e0 + e1 + e2 + e3;
    #pragma unroll
    for (int o = 1; o < 64; o <<= 1) sum += __shfl_xor(sum, o);
    if (lane == 0) reds[wave] = sum;
    __syncthreads();
    sum = reds[0] + reds[1] + reds[2] + reds[3];
    const float inv = 1.0f / sum;

    ushort4 o4;
    o4.x = f2h(e0 * inv); o4.y = f2h(e1 * inv);
    o4.z = f2h(e2 * inv); o4.w = f2h(e3 * inv);
    ((ushort4*)(P + (size_t)row * 1024))[tid] = o4;
}

__global__ void cvt_f32_f16(const float4* __restrict__ in,
                            ushort4* __restrict__ out, int n4)
{
    int i = blockIdx.x * 256 + threadIdx.x;
    const int stride = gridDim.x * 256;
    for (; i < n4; i += stride) {
        const float4 v = in[i];
        ushort4 o;
        o.x = f2h(v.x); o.y = f2h(v.y); o.z = f2h(v.z); o.w = f2h(v.w);
        out[i] = o;
    }
}

extern "C" void kernel_launch(void* const* d_in, const int* in_sizes, int n_in,
                              void* d_out, int out_size, void* d_ws, size_t ws_size,
                              hipStream_t stream)
{
    const float* x  = (const float*)d_in[0];
    const float* Wq = (const float*)d_in[1];
    const float* bq = (const float*)d_in[2];
    const float* Wk = (const float*)d_in[3];
    const float* bk = (const float*)d_in[4];
    const float* Wv = (const float*)d_in[5];
    const float* bv = (const float*)d_in[6];
    float* out = (float*)d_out;

    // Workspace layout (bytes). Total high-water: 339,083,264.
    char* ws = (char*)d_ws;
    unsigned short* xh  = (unsigned short*)(ws + 0);          // 48 MB fp16 x
    unsigned short* wqh = (unsigned short*)(ws + 50331648);
    unsigned short* wkh = (unsigned short*)(ws + 51511296);
    unsigned short* wvh = (unsigned short*)(ws + 52690944);
    unsigned short* Qh  = (unsigned short*)(ws + 53870592);   // 48 MB
    unsigned short* Kh  = (unsigned short*)(ws + 104202240);  // 48 MB
    unsigned short* Vt  = (unsigned short*)(ws + 154533888);  // 48 MB  [b][d][s]
    float*          Sc  = (float*)         (ws + 204865536);  // 128 MB scores
    unsigned short* Ph  = (unsigned short*)(ws + 0);          // 64 MB, reuses x/W/Q (dead)

    // 1) fp32 -> fp16 conversions
    cvt_f32_f16<<<4096, 256, 0, stream>>>((const float4*)x,  (ushort4*)xh,  25165824 / 4);
    cvt_f32_f16<<<576,  256, 0, stream>>>((const float4*)Wq, (ushort4*)wqh, 589824 / 4);
    cvt_f32_f16<<<576,  256, 0, stream>>>((const float4*)Wk, (ushort4*)wkh, 589824 / 4);
    cvt_f32_f16<<<576,  256, 0, stream>>>((const float4*)Wv, (ushort4*)wvh, 589824 / 4);

    const float qscale = 0.03608439182435161f;  // 1/sqrt(768), folded into Q

    // 2) Q = rope(x@Wq^T + bq) * qscale ; K = rope(x@Wk^T + bk)
    gemm_bt<0><<<dim3(6, 256, 1), 256, 0, stream>>>(xh, wqh, Qh, bq, 768, 768, 768, 0, 0, 0, qscale);
    gemm_bt<0><<<dim3(6, 256, 1), 256, 0, stream>>>(xh, wkh, Kh, bk, 768, 768, 768, 0, 0, 0, 1.0f);
    // 3) V^T[b][d][s] via swapped operands: A=Wv (768 rows), B=x (32768 rows)
    gemm_bt<1><<<dim3(256, 6, 1), 256, 0, stream>>>(wvh, xh, Vt, bv, 768, 768, 768, 0, 0, 0, 1.0f);
    // 4) scores[b] = Q[b] @ K[b]^T   (scale already in Q)
    gemm_bt<2><<<dim3(8, 8, 32), 256, 0, stream>>>(Qh, Kh, Sc, nullptr, 768, 768, 768,
                                                   786432, 786432, 1048576, 1.0f);
    // 5) P = softmax(scores) as fp16
    softmax_rows<<<32768, 256, 0, stream>>>(Sc, Ph);
    // 6) out[b] = P[b] @ V[b]  ==  gemm_bt(P, V^T)
    gemm_bt<3><<<dim3(6, 8, 32), 256, 0, stream>>>(Ph, Vt, out, nullptr, 1024, 1024, 1024,
                                                   1048576, 786432, 786432, 1.0f);
}

// Round 2
// 600.151 us; speedup vs baseline: 1.0789x; 1.0789x over previous
//
#include <hip/hip_runtime.h>

// ---------------------------------------------------------------------------
// Fused attention: Q/K/V = x@W^T + b ; RoPE(Q,K) ; softmax(QK^T/sqrt(D)) @ V
// B=32 S=1024 D=768.  fp16 MFMA (16x16x32), fp32 accumulate.
// R2: XCD-aware 1D block swizzle (blocks sharing data -> same XCD via l%8),
//     Q+K projections fused over concatenated Wqk.
// ---------------------------------------------------------------------------

typedef __attribute__((ext_vector_type(8))) _Float16 f16x8;
typedef __attribute__((ext_vector_type(4))) float    f32x4;

__device__ __forceinline__ unsigned short f2h(float f) {
    _Float16 h = (_Float16)f;
    return __builtin_bit_cast(unsigned short, h);
}

__device__ __forceinline__ void async_ld16(const void* g, void* l) {
    __builtin_amdgcn_global_load_lds(
        (const __attribute__((address_space(1))) void*)g,
        (__attribute__((address_space(3))) void*)l, 16, 0, 0);
}

// MODE 0: QK proj: A=x[32768x768], B=Wqk[1536x768]; bias+RoPE; Q*=scale.
//         grid 3072, l = n*256 + m  (same-m co-XCD: x slice fetched once)
// MODE 1: V^T:    A=Wv[768x768],  B=x[32768x768]; bias[row]; out [b][d][s].
//         grid 1536, l = m*256 + n  (same-n co-XCD: x slice fetched once)
// MODE 2: scores: A=Q[b], B=K[b], fp32 out [q][k].
//         grid 2048, l = (m*8+n)*32 + z  (same-z co-XCD: Q[b],K[b] L2-resident)
// MODE 3: PV:     A=P[b], B=Vt[b], fp32 out [q][d] -> d_out.
//         grid 1536, l = (m*6+n)*32 + z
template<int MODE, int KDIM, int LDA, int LDB>
__global__ __launch_bounds__(256)
void gemm_bt(const unsigned short* __restrict__ A,
             const unsigned short* __restrict__ B,
             void* __restrict__ C0, void* __restrict__ C1,
             const float* __restrict__ bias0,
             const float* __restrict__ bias1,
             float scale)
{
    __shared__ __align__(16) unsigned short sA[128 * 32];
    __shared__ __align__(16) unsigned short sB[128 * 32];

    const int tid  = threadIdx.x;
    const int lane = tid & 63;
    const int wave = tid >> 6;
    const int wrow = (wave >> 1) * 64;   // 2x2 wave grid, 64x64 per wave
    const int wcol = (wave & 1) * 64;
    const int quad = lane >> 4;
    const int l15  = lane & 15;

    // --- XCD-aware grid decode (1D) ---
    int m0, n0, z = 0;
    if constexpr (MODE == 0) {
        m0 = (blockIdx.x & 255) * 128;  n0 = (blockIdx.x >> 8) * 128;
    } else if constexpr (MODE == 1) {
        n0 = (blockIdx.x & 255) * 128;  m0 = (blockIdx.x >> 8) * 128;
    } else if constexpr (MODE == 2) {
        z = blockIdx.x & 31; const int q = blockIdx.x >> 5;
        m0 = (q >> 3) * 128; n0 = (q & 7) * 128;
    } else {
        z = blockIdx.x & 31; const int q = blockIdx.x >> 5;
        m0 = (q / 6) * 128;  n0 = (q % 6) * 128;
    }

    const unsigned short* Ab = A;
    const unsigned short* Bb = B;
    if constexpr (MODE == 2) { Ab += (size_t)z * 786432;  Bb += (size_t)z * 786432; }
    if constexpr (MODE == 3) { Ab += (size_t)z * 1048576; Bb += (size_t)z * 786432; }

    const int srow0 = tid >> 2;        // staging row within 64-row half
    const int sk    = (tid & 3) * 8;   // staging k-offset (8 halves = 16B)

    f32x4 acc[4][4] = {};

    for (int kt = 0; kt < KDIM; kt += 32) {
        __syncthreads();
        async_ld16(Ab + (size_t)(m0 +      srow0) * LDA + kt + sk, &sA[tid * 8]);
        async_ld16(Ab + (size_t)(m0 + 64 + srow0) * LDA + kt + sk, &sA[2048 + tid * 8]);
        async_ld16(Bb + (size_t)(n0 +      srow0) * LDB + kt + sk, &sB[tid * 8]);
        async_ld16(Bb + (size_t)(n0 + 64 + srow0) * LDB + kt + sk, &sB[2048 + tid * 8]);
        __syncthreads();

        f16x8 af[4], bfr[4];
        #pragma unroll
        for (int mi = 0; mi < 4; ++mi)
            af[mi] = *(const f16x8*)&sA[(wrow + mi * 16 + l15) * 32 + quad * 8];
        #pragma unroll
        for (int ni = 0; ni < 4; ++ni)
            bfr[ni] = *(const f16x8*)&sB[(wcol + ni * 16 + l15) * 32 + quad * 8];

        #pragma unroll
        for (int mi = 0; mi < 4; ++mi)
            #pragma unroll
            for (int ni = 0; ni < 4; ++ni)
                acc[mi][ni] = __builtin_amdgcn_mfma_f32_16x16x32_f16(
                    af[mi], bfr[ni], acc[mi][ni], 0, 0, 0);
    }

    // Epilogue. C/D layout: col = lane&15, row = quad*4 + reg  [m89-verified]
    #pragma unroll
    for (int mi = 0; mi < 4; ++mi) {
        #pragma unroll
        for (int ni = 0; ni < 4; ++ni) {
            #pragma unroll
            for (int reg = 0; reg < 4; ++reg) {
                const int grow = m0 + wrow + mi * 16 + quad * 4 + reg;
                const int gcol = n0 + wcol + ni * 16 + l15;
                float v = acc[mi][ni][reg];
                if constexpr (MODE == 0) {
                    const bool isQ = gcol < 768;          // block-uniform
                    const int  col = isQ ? gcol : gcol - 768;
                    v += isQ ? bias0[col] : bias1[col];
                    const float other = __shfl_xor(v, 1); // RoPE partner column
                    const int   s     = grow & 1023;
                    // inv_freq[i] = 2^(-i * 2*log2(10000)/768)
                    const float invf  = exp2f((float)(col >> 1) * -0.03460341765507773f);
                    const float ang   = (float)s * invf;
                    float sn, cs;
                    __sincosf(ang, &sn, &cs);
                    float r = (col & 1) ? (other * sn + v * cs)
                                        : (v * cs - other * sn);
                    if (isQ) r *= scale;
                    unsigned short* dst = (unsigned short*)(isQ ? C0 : C1);
                    dst[(size_t)grow * 768 + col] = f2h(r);
                } else if constexpr (MODE == 1) {
                    v += bias0[grow];  // output feature = row (d)
                    const int b = gcol >> 10, s = gcol & 1023;
                    ((unsigned short*)C0)[(size_t)b * (768 * 1024)
                                          + (size_t)grow * 1024 + s] = f2h(v);
                } else if constexpr (MODE == 2) {
                    (((float*)C0) + (size_t)z * 1048576)[(size_t)grow * 1024 + gcol] = v;
                } else {
                    (((float*)C0) + (size_t)z * 786432)[(size_t)grow * 768 + gcol] = v;
                }
            }
        }
    }
}

__global__ __launch_bounds__(256)
void softmax_rows(const float* __restrict__ S, unsigned short* __restrict__ P)
{
    const int row = blockIdx.x;           // 32*1024 rows
    const int tid = threadIdx.x;
    const float4 v = ((const float4*)(S + (size_t)row * 1024))[tid];

    float m = fmaxf(fmaxf(v.x, v.y), fmaxf(v.z, v.w));
    #pragma unroll
    for (int o = 1; o < 64; o <<= 1) m = fmaxf(m, __shfl_xor(m, o));
    __shared__ float redm[4];
    __shared__ float reds[4];
    const int wave = tid >> 6, lane = tid & 63;
    if (lane == 0) redm[wave] = m;
    __syncthreads();
    m = fmaxf(fmaxf(redm[0], redm[1]), fmaxf(redm[2], redm[3]));

    const float e0 = __expf(v.x - m), e1 = __expf(v.y - m);
    const float e2 = __expf(v.z - m), e3 = __expf(v.w - m);
    float sum = e0 + e1 + e2 + e3;
    #pragma unroll
    for (int o = 1; o < 64; o <<= 1) sum += __shfl_xor(sum, o);
    if (lane == 0) reds[wave] = sum;
    __syncthreads();
    sum = reds[0] + reds[1] + reds[2] + reds[3];
    const float inv = 1.0f / sum;

    ushort4 o4;
    o4.x = f2h(e0 * inv); o4.y = f2h(e1 * inv);
    o4.z = f2h(e2 * inv); o4.w = f2h(e3 * inv);
    ((ushort4*)(P + (size_t)row * 1024))[tid] = o4;
}

__global__ void cvt_f32_f16(const float4* __restrict__ in,
                            ushort4* __restrict__ out, int n4)
{
    int i = blockIdx.x * 256 + threadIdx.x;
    const int stride = gridDim.x * 256;
    for (; i < n4; i += stride) {
        const float4 v = in[i];
        ushort4 o;
        o.x = f2h(v.x); o.y = f2h(v.y); o.z = f2h(v.z); o.w = f2h(v.w);
        out[i] = o;
    }
}

extern "C" void kernel_launch(void* const* d_in, const int* in_sizes, int n_in,
                              void* d_out, int out_size, void* d_ws, size_t ws_size,
                              hipStream_t stream)
{
    const float* x  = (const float*)d_in[0];
    const float* Wq = (const float*)d_in[1];
    const float* bq = (const float*)d_in[2];
    const float* Wk = (const float*)d_in[3];
    const float* bk = (const float*)d_in[4];
    const float* Wv = (const float*)d_in[5];
    const float* bv = (const float*)d_in[6];
    float* out = (float*)d_out;

    // Workspace layout (bytes). High-water: 339,083,264.
    char* ws = (char*)d_ws;
    unsigned short* xh  = (unsigned short*)(ws + 0);          // 48 MB fp16 x
    unsigned short* wqk = (unsigned short*)(ws + 50331648);   // Wq||Wk [1536][768]
    unsigned short* wvh = (unsigned short*)(ws + 52690944);
    unsigned short* Qh  = (unsigned short*)(ws + 53870592);   // 48 MB
    unsigned short* Kh  = (unsigned short*)(ws + 104202240);  // 48 MB
    unsigned short* Vt  = (unsigned short*)(ws + 154533888);  // 48 MB  [b][d][s]
    float*          Sc  = (float*)         (ws + 204865536);  // 128 MB scores
    unsigned short* Ph  = (unsigned short*)(ws + 0);          // 64 MB (x/W/Qh-head dead)

    // 1) fp32 -> fp16 conversions
    cvt_f32_f16<<<4096, 256, 0, stream>>>((const float4*)x,  (ushort4*)xh, 25165824 / 4);
    cvt_f32_f16<<<576,  256, 0, stream>>>((const float4*)Wq, (ushort4*)wqk, 589824 / 4);
    cvt_f32_f16<<<576,  256, 0, stream>>>((const float4*)Wk, (ushort4*)(wqk + 589824), 589824 / 4);
    cvt_f32_f16<<<576,  256, 0, stream>>>((const float4*)Wv, (ushort4*)wvh, 589824 / 4);

    const float qscale = 0.03608439182435161f;  // 1/sqrt(768), folded into Q

    // 2) Q,K = rope(x@Wqk^T + b) (Q scaled); fused over concatenated Wqk
    gemm_bt<0, 768, 768, 768><<<3072, 256, 0, stream>>>(
        xh, wqk, Qh, Kh, bq, bk, qscale);
    // 3) V^T[b][d][s] via swapped operands
    gemm_bt<1, 768, 768, 768><<<1536, 256, 0, stream>>>(
        wvh, xh, Vt, nullptr, bv, nullptr, 1.0f);
    // 4) scores[b] = Q[b] @ K[b]^T  (scale already in Q)
    gemm_bt<2, 768, 768, 768><<<2048, 256, 0, stream>>>(
        Qh, Kh, Sc, nullptr, nullptr, nullptr, 1.0f);
    // 5) P = softmax(scores) as fp16
    softmax_rows<<<32768, 256, 0, stream>>>(Sc, Ph);
    // 6) out[b] = P[b] @ V[b] == gemm_bt(P, V^T)
    gemm_bt<3, 1024, 1024, 1024><<<1536, 256, 0, stream>>>(
        Ph, Vt, out, nullptr, nullptr, nullptr, 1.0f);
}

// Round 3
// 572.390 us; speedup vs baseline: 1.1312x; 1.0485x over previous
//
#include <hip/hip_runtime.h>

// ---------------------------------------------------------------------------
// Fused attention: Q/K/V = x@W^T + b ; RoPE(Q,K) ; softmax(QK^T/sqrt(D)) @ V
// B=32 S=1024 D=768.  fp16 MFMA (16x16x32), fp32 accumulate.
// R3: BK=64 with XOR-swizzled LDS (kills 16-way conflicts while keeping
//     global_load_lds contiguity), pair-packed epilogue stores, fp16 scores.
// ---------------------------------------------------------------------------

typedef __attribute__((ext_vector_type(8))) _Float16 f16x8;
typedef __attribute__((ext_vector_type(4))) float    f32x4;

__device__ __forceinline__ unsigned short f2h(float f) {
    _Float16 h = (_Float16)f;
    return __builtin_bit_cast(unsigned short, h);
}
__device__ __forceinline__ float h2f(unsigned short u) {
    return (float)__builtin_bit_cast(_Float16, u);
}

__device__ __forceinline__ void async_ld16(const void* g, void* l) {
    __builtin_amdgcn_global_load_lds(
        (const __attribute__((address_space(1))) void*)g,
        (__attribute__((address_space(3))) void*)l, 16, 0, 0);
}

// MODE 0: QK proj: A=x[32768x768], B=Wqk[1536x768]; bias+RoPE; Q*=scale.
//         grid 3072, l = n*256 + m  (same-m co-XCD: x slice fetched once)
// MODE 1: V^T:    A=Wv[768x768],  B=x[32768x768]; bias[row]; out [b][d][s].
//         grid 1536, l = m*256 + n
// MODE 2: scores: A=Q[b], B=K[b], fp16 out [q][k].
//         grid 2048, l = (m*8+n)*32 + z  (same-z co-XCD)
// MODE 3: PV:     A=P[b], B=Vt[b], fp32 out [q][d] -> d_out.
//         grid 1536, l = (m*6+n)*32 + z
template<int MODE, int KDIM, int LDA, int LDB>
__global__ __launch_bounds__(256)
void gemm_bt(const unsigned short* __restrict__ A,
             const unsigned short* __restrict__ B,
             void* __restrict__ C0, void* __restrict__ C1,
             const float* __restrict__ bias0,
             const float* __restrict__ bias1,
             float scale)
{
    // BK=64: row stride 64 halves (128 B). Physical 16B-chunk p of row r
    // holds logical k-chunk p^(r&7)  -> fragment reads spread 8 bank groups.
    __shared__ __align__(16) unsigned short sA[128 * 64];
    __shared__ __align__(16) unsigned short sB[128 * 64];

    const int tid  = threadIdx.x;
    const int lane = tid & 63;
    const int wave = tid >> 6;
    const int wrow = (wave >> 1) * 64;   // 2x2 wave grid, 64x64 per wave
    const int wcol = (wave & 1) * 64;
    const int quad = lane >> 4;
    const int l15  = lane & 15;

    // --- XCD-aware grid decode (1D) ---
    int m0, n0, z = 0;
    if constexpr (MODE == 0) {
        m0 = (blockIdx.x & 255) * 128;  n0 = (blockIdx.x >> 8) * 128;
    } else if constexpr (MODE == 1) {
        n0 = (blockIdx.x & 255) * 128;  m0 = (blockIdx.x >> 8) * 128;
    } else if constexpr (MODE == 2) {
        z = blockIdx.x & 31; const int q = blockIdx.x >> 5;
        m0 = (q >> 3) * 128; n0 = (q & 7) * 128;
    } else {
        z = blockIdx.x & 31; const int q = blockIdx.x >> 5;
        m0 = (q / 6) * 128;  n0 = (q % 6) * 128;
    }

    const unsigned short* Ab = A;
    const unsigned short* Bb = B;
    if constexpr (MODE == 2) { Ab += (size_t)z * 786432;  Bb += (size_t)z * 786432; }
    if constexpr (MODE == 3) { Ab += (size_t)z * 1048576; Bb += (size_t)z * 786432; }

    // Staging: 4 instr/matrix, each covers 32 rows x 8 chunks of 16B.
    const int srow = tid >> 3;                       // 0..31
    const int sk   = ((tid & 7) ^ (srow & 7)) * 8;   // swizzled logical k-chunk

    f32x4 acc[4][4] = {};

    for (int kt = 0; kt < KDIM; kt += 64) {
        __syncthreads();
        #pragma unroll
        for (int g = 0; g < 4; ++g) {
            async_ld16(Ab + (size_t)(m0 + g * 32 + srow) * LDA + kt + sk,
                       &sA[g * 2048 + tid * 8]);
            async_ld16(Bb + (size_t)(n0 + g * 32 + srow) * LDB + kt + sk,
                       &sB[g * 2048 + tid * 8]);
        }
        __syncthreads();

        #pragma unroll
        for (int kk = 0; kk < 2; ++kk) {
            f16x8 af[4], bfr[4];
            #pragma unroll
            for (int mi = 0; mi < 4; ++mi) {
                const int r = wrow + mi * 16 + l15;
                af[mi] = *(const f16x8*)&sA[r * 64 + (((kk * 4 + quad) ^ (r & 7)) << 3)];
            }
            #pragma unroll
            for (int ni = 0; ni < 4; ++ni) {
                const int r = wcol + ni * 16 + l15;
                bfr[ni] = *(const f16x8*)&sB[r * 64 + (((kk * 4 + quad) ^ (r & 7)) << 3)];
            }
            #pragma unroll
            for (int mi = 0; mi < 4; ++mi)
                #pragma unroll
                for (int ni = 0; ni < 4; ++ni)
                    acc[mi][ni] = __builtin_amdgcn_mfma_f32_16x16x32_f16(
                        af[mi], bfr[ni], acc[mi][ni], 0, 0, 0);
        }
    }

    // Epilogue. C/D layout: col = lane&15, row = quad*4 + reg  [m89-verified]
    // Adjacent cols sit in adjacent lanes -> pair-pack, even lanes store.
    const bool evenlane = (l15 & 1) == 0;

    float invf[4];
    if constexpr (MODE == 0) {
        #pragma unroll
        for (int ni = 0; ni < 4; ++ni) {
            int col = n0 + wcol + ni * 16 + l15;
            if (col >= 768) col -= 768;
            // inv_freq[i] = 2^(-i * 2*log2(10000)/768)
            invf[ni] = exp2f((float)(col >> 1) * -0.03460341765507773f);
        }
    }

    #pragma unroll
    for (int mi = 0; mi < 4; ++mi) {
        #pragma unroll
        for (int ni = 0; ni < 4; ++ni) {
            #pragma unroll
            for (int reg = 0; reg < 4; ++reg) {
                const int grow = m0 + wrow + mi * 16 + quad * 4 + reg;
                const int gcol = n0 + wcol + ni * 16 + l15;
                float v = acc[mi][ni][reg];
                if constexpr (MODE == 0) {
                    const bool isQ = gcol < 768;          // block-uniform
                    const int  col = isQ ? gcol : gcol - 768;
                    v += isQ ? bias0[col] : bias1[col];
                    const float other = __shfl_xor(v, 1); // RoPE partner column
                    const int   s     = grow & 1023;
                    const float ang   = (float)s * invf[ni];
                    float sn, cs;
                    __sincosf(ang, &sn, &cs);
                    float r = (col & 1) ? fmaf(other, sn, v * cs)
                                        : fmaf(v, cs, -(other * sn));
                    if (isQ) r *= scale;
                    const unsigned short h = f2h(r);
                    const unsigned int packed =
                        (unsigned int)h | (__shfl_xor((unsigned int)h, 1) << 16);
                    if (evenlane) {
                        unsigned short* dst = (unsigned short*)(isQ ? C0 : C1);
                        *(unsigned int*)(dst + (size_t)grow * 768 + col) = packed;
                    }
                } else if constexpr (MODE == 1) {
                    v += bias0[grow];  // output feature = row (d)
                    const unsigned short h = f2h(v);
                    const unsigned int packed =
                        (unsigned int)h | (__shfl_xor((unsigned int)h, 1) << 16);
                    if (evenlane) {
                        const int b = gcol >> 10, s = gcol & 1023;
                        *(unsigned int*)((unsigned short*)C0 + (size_t)b * (768 * 1024)
                                         + (size_t)grow * 1024 + s) = packed;
                    }
                } else if constexpr (MODE == 2) {
                    const unsigned short h = f2h(v);
                    const unsigned int packed =
                        (unsigned int)h | (__shfl_xor((unsigned int)h, 1) << 16);
                    if (evenlane) {
                        *(unsigned int*)((unsigned short*)C0 + (size_t)z * 1048576
                                         + (size_t)grow * 1024 + gcol) = packed;
                    }
                } else {
                    const float vo = __shfl_xor(v, 1);
                    if (evenlane) {
                        float2 p; p.x = v; p.y = vo;
                        *(float2*)(((float*)C0) + (size_t)z * 786432
                                   + (size_t)grow * 768 + gcol) = p;
                    }
                }
            }
        }
    }
}

__global__ __launch_bounds__(256)
void softmax_rows(const unsigned short* __restrict__ S, unsigned short* __restrict__ P)
{
    const int row = blockIdx.x;           // 32*1024 rows
    const int tid = threadIdx.x;
    const ushort4 u = ((const ushort4*)(S + (size_t)row * 1024))[tid];
    const float v0 = h2f(u.x), v1 = h2f(u.y), v2 = h2f(u.z), v3 = h2f(u.w);

    float m = fmaxf(fmaxf(v0, v1), fmaxf(v2, v3));
    #pragma unroll
    for (int o = 1; o < 64; o <<= 1) m = fmaxf(m, __shfl_xor(m, o));
    __shared__ float redm[4];
    __shared__ float reds[4];
    const int wave = tid >> 6, lane = tid & 63;
    if (lane == 0) redm[wave] = m;
    __syncthreads();
    m = fmaxf(fmaxf(redm[0], redm[1]), fmaxf(redm[2], redm[3]));

    const float e0 = __expf(v0 - m), e1 = __expf(v1 - m);
    const float e2 = __expf(v2 - m), e3 = __expf(v3 - m);
    float sum = e0 + e1 + e2 + e3;
    #pragma unroll
    for (int o = 1; o < 64; o <<= 1) sum += __shfl_xor(sum, o);
    if (lane == 0) reds[wave] = sum;
    __syncthreads();
    sum = reds[0] + reds[1] + reds[2] + reds[3];
    const float inv = 1.0f / sum;

    ushort4 o4;
    o4.x = f2h(e0 * inv); o4.y = f2h(e1 * inv);
    o4.z = f2h(e2 * inv); o4.w = f2h(e3 * inv);
    ((ushort4*)(P + (size_t)row * 1024))[tid] = o4;
}

__global__ void cvt_f32_f16(const float4* __restrict__ in,
                            ushort4* __restrict__ out, int n4)
{
    int i = blockIdx.x * 256 + threadIdx.x;
    const int stride = gridDim.x * 256;
    for (; i < n4; i += stride) {
        const float4 v = in[i];
        ushort4 o;
        o.x = f2h(v.x); o.y = f2h(v.y); o.z = f2h(v.z); o.w = f2h(v.w);
        out[i] = o;
    }
}

extern "C" void kernel_launch(void* const* d_in, const int* in_sizes, int n_in,
                              void* d_out, int out_size, void* d_ws, size_t ws_size,
                              hipStream_t stream)
{
    const float* x  = (const float*)d_in[0];
    const float* Wq = (const float*)d_in[1];
    const float* bq = (const float*)d_in[2];
    const float* Wk = (const float*)d_in[3];
    const float* bk = (const float*)d_in[4];
    const float* Wv = (const float*)d_in[5];
    const float* bv = (const float*)d_in[6];
    float* out = (float*)d_out;

    // Workspace layout (bytes). High-water: ~272 MB.
    char* ws = (char*)d_ws;
    unsigned short* xh  = (unsigned short*)(ws + 0);          // 48 MB fp16 x
    unsigned short* wqk = (unsigned short*)(ws + 50331648);   // Wq||Wk [1536][768]
    unsigned short* wvh = (unsigned short*)(ws + 52690944);
    unsigned short* Qh  = (unsigned short*)(ws + 53870592);   // 48 MB
    unsigned short* Kh  = (unsigned short*)(ws + 104202240);  // 48 MB
    unsigned short* Vt  = (unsigned short*)(ws + 154533888);  // 48 MB  [b][d][s]
    unsigned short* Sc  = (unsigned short*)(ws + 204865536);  // 64 MB fp16 scores
    unsigned short* Ph  = (unsigned short*)(ws + 0);          // 64 MB (x/W dead)

    // 1) fp32 -> fp16 conversions
    cvt_f32_f16<<<4096, 256, 0, stream>>>((const float4*)x,  (ushort4*)xh, 25165824 / 4);
    cvt_f32_f16<<<576,  256, 0, stream>>>((const float4*)Wq, (ushort4*)wqk, 589824 / 4);
    cvt_f32_f16<<<576,  256, 0, stream>>>((const float4*)Wk, (ushort4*)(wqk + 589824), 589824 / 4);
    cvt_f32_f16<<<576,  256, 0, stream>>>((const float4*)Wv, (ushort4*)wvh, 589824 / 4);

    const float qscale = 0.03608439182435161f;  // 1/sqrt(768), folded into Q

    // 2) Q,K = rope(x@Wqk^T + b) (Q scaled); fused over concatenated Wqk
    gemm_bt<0, 768, 768, 768><<<3072, 256, 0, stream>>>(
        xh, wqk, Qh, Kh, bq, bk, qscale);
    // 3) V^T[b][d][s] via swapped operands
    gemm_bt<1, 768, 768, 768><<<1536, 256, 0, stream>>>(
        wvh, xh, Vt, nullptr, bv, nullptr, 1.0f);
    // 4) scores[b] = Q[b] @ K[b]^T  (scale already in Q), fp16 out
    gemm_bt<2, 768, 768, 768><<<2048, 256, 0, stream>>>(
        Qh, Kh, Sc, nullptr, nullptr, nullptr, 1.0f);
    // 5) P = softmax(scores) as fp16
    softmax_rows<<<32768, 256, 0, stream>>>(Sc, Ph);
    // 6) out[b] = P[b] @ V[b] == gemm_bt(P, V^T)
    gemm_bt<3, 1024, 1024, 1024><<<1536, 256, 0, stream>>>(
        Ph, Vt, out, nullptr, nullptr, nullptr, 1.0f);
}